// Round 5
// baseline (382.446 us; speedup 1.0000x reference)
//
#include <hip/hip_runtime.h>
#include <hip/hip_bf16.h>
#include <cstdint>
#include <cstddef>

// B=4, S=2048, D=768 causal attention, fp32 in/out, f16 MFMA compute.
// cvt -> QKV GEMM (Q pre-scaled) -> QK^T GEMM (epilogue: exp+rowsum atomics)
//     -> PV GEMM (epilogue: *1/rowsum). No separate softmax pass.
// GEMM K-loop: NO LDS, NO barriers. Each wave loads its MFMA fragments
// directly from global (fragment layout == row-major rows x 16B k-chunks),
// 4-deep register double-buffering, prefetch distance 3 -> ~24 loads in
// flight per wave, self-paced via compiler vmcnt. Latency-tolerant by ILP.

typedef _Float16 f16x8 __attribute__((ext_vector_type(8)));
typedef float    f32x4 __attribute__((ext_vector_type(4)));

#define SOFTMAX_SCALE 0.036084391824351615f  // 1/sqrt(768)

// EPI 0: QKV projection epilogue (Q*scale/K flat f16, V transposed per batch)
// EPI 1: E = exp(S) f16 (causal-masked), rowsum atomics; triangular grid
// EPI 2: output fp32 * 1/rowsum[m], K-loop truncated causally, heavy-tm first
template <int EPI>
__global__ __launch_bounds__(256, 2) void gemm_bt(
    const _Float16* __restrict__ A, const _Float16* __restrict__ B,
    float* __restrict__ CF, _Float16* __restrict__ CH,
    _Float16* __restrict__ OQ, _Float16* __restrict__ OKk, _Float16* __restrict__ OV,
    float* __restrict__ rowsum,
    int K, int lda, int ldb, int ldc,
    long long batchA, long long batchB, long long batchC)
{
    int tm, tn, bz;
    if (EPI == 1) {
        // triangular decode: 136 lower-triangle tiles per batch
        const int idx = blockIdx.x;
        bz = idx / 136;
        const int t = idx - bz * 136;
        tm = (int)((__builtin_sqrtf(8.f * t + 1.f) - 1.f) * 0.5f);
        while ((tm + 1) * (tm + 2) / 2 <= t) ++tm;
        while (tm * (tm + 1) / 2 > t) --tm;
        tn = t - tm * (tm + 1) / 2;
    } else if (EPI == 2) {
        tm = (int)gridDim.y - 1 - (int)blockIdx.y;   // heavy tiles first
        tn = blockIdx.x; bz = blockIdx.z;
    } else {
        tm = blockIdx.y; tn = blockIdx.x; bz = blockIdx.z;
    }

    const int m0 = tm * 128, n0 = tn * 128;
    const int tid  = threadIdx.x;
    const int lane = tid & 63, wave = tid >> 6;
    const int wm = (wave >> 1) * 64, wn = (wave & 1) * 64;
    const int qr = lane >> 4, ql = lane & 15;

    const _Float16* Ab = A + (long long)bz * batchA + (long long)m0 * lda;
    const _Float16* Bb = B + (long long)bz * batchB + (long long)n0 * ldb;

    // Per-lane fragment row pointers: A[m=ql][k=qr*8+j] for mfma 16x16x32.
    const _Float16* pa[4];
    const _Float16* pb[4];
#pragma unroll
    for (int mi = 0; mi < 4; ++mi)
        pa[mi] = Ab + (long long)(wm + mi * 16 + ql) * lda + qr * 8;
#pragma unroll
    for (int ni = 0; ni < 4; ++ni)
        pb[ni] = Bb + (long long)(wn + ni * 16 + ql) * ldb + qr * 8;

    int kIters = K / 32;                    // BK=32 per step
    if (EPI == 2) kIters = (tm + 1) * 4;    // E is zero beyond (tm+1)*128

    f32x4 acc[4][4];
#pragma unroll
    for (int i = 0; i < 4; ++i)
#pragma unroll
        for (int j = 0; j < 4; ++j) acc[i][j] = (f32x4){0.f, 0.f, 0.f, 0.f};

    f16x8 fa[4][4], fb[4][4];   // 4-stage register pipeline

    auto loadset = [&](int kt, int buf) {
        const int kk = kt * 32;
#pragma unroll
        for (int mi = 0; mi < 4; ++mi) fa[buf][mi] = *(const f16x8*)(pa[mi] + kk);
#pragma unroll
        for (int ni = 0; ni < 4; ++ni) fb[buf][ni] = *(const f16x8*)(pb[ni] + kk);
    };
    auto mfmaset = [&](int buf) {
#pragma unroll
        for (int mi = 0; mi < 4; ++mi)
#pragma unroll
            for (int ni = 0; ni < 4; ++ni)
                acc[mi][ni] = __builtin_amdgcn_mfma_f32_16x16x32_f16(
                    fa[buf][mi], fb[buf][ni], acc[mi][ni], 0, 0, 0);
    };

    // kIters is always a multiple of 4 and >= 4.
    loadset(0, 0); loadset(1, 1); loadset(2, 2);
    for (int kt4 = 0; kt4 < kIters; kt4 += 4) {
        if (kt4 + 3 < kIters) loadset(kt4 + 3, 3);
        mfmaset(0);
        if (kt4 + 4 < kIters) loadset(kt4 + 4, 0);
        mfmaset(1);
        if (kt4 + 5 < kIters) loadset(kt4 + 5, 1);
        mfmaset(2);
        if (kt4 + 6 < kIters) loadset(kt4 + 6, 2);
        mfmaset(3);
    }

    // Epilogue. C/D frag: col = lane&15, row = (lane>>4)*4 + r
    const long long zC = (long long)bz * batchC;
    float rsum[4][4];
    if (EPI == 1) {
#pragma unroll
        for (int mi = 0; mi < 4; ++mi)
#pragma unroll
            for (int r = 0; r < 4; ++r) rsum[mi][r] = 0.f;
    }

#pragma unroll
    for (int mi = 0; mi < 4; ++mi) {
        float invl[4];
        if (EPI == 2) {
#pragma unroll
            for (int r = 0; r < 4; ++r)
                invl[r] = 1.f / rowsum[bz * 2048 + m0 + wm + mi * 16 + qr * 4 + r];
        }
#pragma unroll
        for (int ni = 0; ni < 4; ++ni) {
            const f32x4 v = acc[mi][ni];
            const int mbase = m0 + wm + mi * 16 + qr * 4;
            const int n     = n0 + wn + ni * 16 + ql;
#pragma unroll
            for (int r = 0; r < 4; ++r) {
                const int m = mbase + r;
                const float val = v[r];
                if (EPI == 0) {
                    const int b = m >> 11, s = m & 2047;
                    if (n < 768)
                        OQ[(long long)m * 768 + n] = (_Float16)(val * SOFTMAX_SCALE);
                    else if (n < 1536)
                        OKk[(long long)m * 768 + (n - 768)] = (_Float16)val;
                    else
                        OV[((long long)b * 768 + (n - 1536)) * 2048 + s] = (_Float16)val;
                } else if (EPI == 1) {
                    const float e = (n <= m) ? __expf(val) : 0.f;
                    CH[zC + (long long)m * ldc + n] = (_Float16)e;
                    rsum[mi][r] += e;
                } else {
                    CF[zC + (long long)m * ldc + n] = val * invl[r];
                }
            }
        }
    }

    if (EPI == 1) {
#pragma unroll
        for (int mi = 0; mi < 4; ++mi)
#pragma unroll
            for (int r = 0; r < 4; ++r) {
                float s = rsum[mi][r];
                s += __shfl_xor(s, 1);
                s += __shfl_xor(s, 2);
                s += __shfl_xor(s, 4);
                s += __shfl_xor(s, 8);
                if (ql == 0) {
                    const int m = m0 + wm + mi * 16 + qr * 4 + r;
                    atomicAdd(&rowsum[bz * 2048 + m], s);
                }
            }
    }
}

__global__ __launch_bounds__(256) void cvt_x(
    const float* __restrict__ in, _Float16* __restrict__ out)
{
    const int i = blockIdx.x * 256 + threadIdx.x;   // one per 8 elements
    const float4 v0 = ((const float4*)in)[i * 2];
    const float4 v1 = ((const float4*)in)[i * 2 + 1];
    f16x8 o = { (_Float16)v0.x, (_Float16)v0.y, (_Float16)v0.z, (_Float16)v0.w,
                (_Float16)v1.x, (_Float16)v1.y, (_Float16)v1.z, (_Float16)v1.w };
    ((f16x8*)out)[i] = o;
}

__global__ __launch_bounds__(256) void cvt_w3(
    const float* __restrict__ s0, const float* __restrict__ s1,
    const float* __restrict__ s2, _Float16* __restrict__ out)
{
    const int idx = blockIdx.x * 256 + threadIdx.x;  // one per 8 elements
    const int per = 768 * 768 / 8;
    const int w = idx / per;                         // wave-uniform
    const float* s = (w == 0) ? s0 : (w == 1) ? s1 : s2;
    const int lo = idx - w * per;
    const float4 v0 = ((const float4*)s)[lo * 2];
    const float4 v1 = ((const float4*)s)[lo * 2 + 1];
    f16x8 o = { (_Float16)v0.x, (_Float16)v0.y, (_Float16)v0.z, (_Float16)v0.w,
                (_Float16)v1.x, (_Float16)v1.y, (_Float16)v1.z, (_Float16)v1.w };
    ((f16x8*)out)[idx] = o;
}

extern "C" void kernel_launch(void* const* d_in, const int* in_sizes, int n_in,
                              void* d_out, int out_size, void* d_ws, size_t ws_size,
                              hipStream_t stream) {
    const float* x  = (const float*)d_in[0];
    const float* wq = (const float*)d_in[1];
    const float* wk = (const float*)d_in[2];
    const float* wv = (const float*)d_in[3];
    float* out = (float*)d_out;
    char* ws = (char*)d_ws;

    size_t off = 0;
    auto alloc = [&](size_t bytes) {
        void* p = ws + off;
        off = (off + bytes + 255) & ~(size_t)255;
        return p;
    };
    _Float16* xh = (_Float16*)alloc(8192ll * 768 * 2);
    _Float16* Wh = (_Float16*)alloc(2304ll * 768 * 2);
    _Float16* Qh = (_Float16*)alloc(8192ll * 768 * 2);   // pre-scaled by 1/sqrt(d)
    _Float16* Kh = (_Float16*)alloc(8192ll * 768 * 2);
    _Float16* Vt = (_Float16*)alloc(4ll * 768 * 2048 * 2);     // V^T per batch
    _Float16* E  = (_Float16*)alloc(4ll * 2048 * 2048 * 2);    // exp(scores) f16
    float*    rs = (float*)   alloc(8192ll * 4);               // row sums

    hipMemsetAsync(rs, 0, 8192 * 4, stream);
    cvt_x<<<8192 * 768 / 8 / 256, 256, 0, stream>>>(x, xh);
    cvt_w3<<<3 * 288, 256, 0, stream>>>(wq, wk, wv, Wh);

    // Y = x * W^T : M=8192, N=2304, K=768
    gemm_bt<0><<<dim3(18, 64, 1), 256, 0, stream>>>(
        xh, Wh, nullptr, nullptr, Qh, Kh, Vt, nullptr,
        768, 768, 768, 0, 0, 0, 0);

    // E = exp(Q K^T) per batch, rowsum atomics (lower triangle only)
    gemm_bt<1><<<dim3(136 * 4, 1, 1), 256, 0, stream>>>(
        Qh, Kh, nullptr, E, nullptr, nullptr, nullptr, rs,
        768, 768, 768, 2048, 2048ll * 768, 2048ll * 768, 2048ll * 2048);

    // O = (E * V^T^T) / rowsum per batch : M=2048, N=768, K causal-truncated
    gemm_bt<2><<<dim3(6, 16, 4), 256, 0, stream>>>(
        E, Vt, out, nullptr, nullptr, nullptr, nullptr, rs,
        2048, 2048, 2048, 768, 2048ll * 2048, 768ll * 2048, 2048ll * 768);
}

// Round 6
// 217.065 us; speedup vs baseline: 1.7619x; 1.7619x over previous
//
#include <hip/hip_runtime.h>
#include <hip/hip_bf16.h>
#include <cstdint>
#include <cstddef>

// B=4, S=2048, D=768 causal attention, fp32 in/out, f16 MFMA compute.
// cvt(+zero rowsum) -> QKV GEMM (Q pre-scaled) -> QK^T GEMM (exp+rowsum
// atomics) -> PV GEMM (*1/rowsum). No separate softmax pass.
// GEMM: wave tile MI*16 x 64 (MI=8 -> block 256x128; MI=4 -> 128x128),
// BK=64, XOR-swizzled single LDS buffer, register-prefetch pipeline.
// Rationale: 64x64 wave tiles are LDS-BW-bound (32.8 FLOP/LDS-byte);
// 128x64 gives 87 FLOP/B -> MFMA-bound.

typedef _Float16 f16x8 __attribute__((ext_vector_type(8)));
typedef float    f32x4 __attribute__((ext_vector_type(4)));

#define SOFTMAX_SCALE 0.036084391824351615f  // 1/sqrt(768)

// EPI 0: QKV projection epilogue (Q*scale/K flat f16, V transposed per batch)
// EPI 1: E = exp(S) f16 (causal-masked), rowsum atomics; triangular grid
// EPI 2: output fp32 * 1/rowsum[m], K-loop truncated causally, heavy-tm first
// MI: A-fragment rows per wave (wave tile = MI*16 x 64; block = MI*32 x 128)
template <int EPI, int MI>
__global__ __launch_bounds__(256, 2) void gemm_bt(
    const _Float16* __restrict__ A, const _Float16* __restrict__ B,
    float* __restrict__ CF, _Float16* __restrict__ CH,
    _Float16* __restrict__ OQ, _Float16* __restrict__ OKk, _Float16* __restrict__ OV,
    float* __restrict__ rowsum,
    int K, int lda, int ldb, int ldc,
    long long batchA, long long batchB, long long batchC)
{
    constexpr int BM = MI * 32;          // block rows
    int tm, tn, bz;
    if (EPI == 1) {
        // triangular decode over 256-row x 128-col tiles: 72 per batch
        const int idx = blockIdx.x;
        bz = idx / 72;
        const int t = idx - bz * 72;
        tm = (int)((__builtin_sqrtf(4.f * t + 1.f) - 1.f) * 0.5f);
        while ((tm + 1) * (tm + 2) <= t) ++tm;
        while (tm * (tm + 1) > t) --tm;
        tn = t - tm * (tm + 1);
    } else if (EPI == 2) {
        tm = (int)gridDim.y - 1 - (int)blockIdx.y;   // heavy tiles first
        tn = blockIdx.x; bz = blockIdx.z;
    } else {
        tm = blockIdx.y; tn = blockIdx.x; bz = blockIdx.z;
    }

    const int m0 = tm * BM, n0 = tn * 128;
    const int tid  = threadIdx.x;
    const int lane = tid & 63, wave = tid >> 6;
    const int wm = (wave >> 1) * (MI * 16), wn = (wave & 1) * 64;
    const int qr = lane >> 4, ql = lane & 15;

    __shared__ _Float16 sA[BM * 64];
    __shared__ _Float16 sB[128 * 64];

    const _Float16* Ab = A + (long long)bz * batchA + (long long)m0 * lda;
    const _Float16* Bb = B + (long long)bz * batchB + (long long)n0 * ldb;

    int kIters = K / 64;
    if (EPI == 2) kIters = (tm + 1) * 2;   // E is zero beyond (tm+1)*128

    f32x4 acc[MI][4];
#pragma unroll
    for (int i = 0; i < MI; ++i)
#pragma unroll
        for (int j = 0; j < 4; ++j) acc[i][j] = (f32x4){0.f, 0.f, 0.f, 0.f};

    // Staging: 16B chunk c = t*256 + tid at LDS slot c; slot c holds global
    // chunk (c&7)^(row&7) of row=c>>3 (XOR swizzle; readers XOR the same
    // way -> conflict-free b128 on both sides; measured 0 conflicts).
    int sraA[MI], sgcA[MI], sraB[4], sgcB[4];
#pragma unroll
    for (int t = 0; t < MI; ++t) {
        const int c = t * 256 + tid, r = c >> 3;
        sraA[t] = r; sgcA[t] = (c & 7) ^ (r & 7);
    }
#pragma unroll
    for (int t = 0; t < 4; ++t) {
        const int c = t * 256 + tid, r = c >> 3;
        sraB[t] = r; sgcB[t] = (c & 7) ^ (r & 7);
    }

    f16x8 pa[MI], pb[4];
    auto loadset = [&](int kt) {
        const int kk = kt * 64;
#pragma unroll
        for (int t = 0; t < MI; ++t)
            pa[t] = *(const f16x8*)(Ab + (long long)sraA[t] * lda + kk + sgcA[t] * 8);
#pragma unroll
        for (int t = 0; t < 4; ++t)
            pb[t] = *(const f16x8*)(Bb + (long long)sraB[t] * ldb + kk + sgcB[t] * 8);
    };

    loadset(0);
    for (int kt = 0; kt < kIters; ++kt) {
        // commit prefetched tile kt to LDS (vmcnt waits happen here)
#pragma unroll
        for (int t = 0; t < MI; ++t) ((f16x8*)sA)[t * 256 + tid] = pa[t];
#pragma unroll
        for (int t = 0; t < 4; ++t) ((f16x8*)sB)[t * 256 + tid] = pb[t];
        __syncthreads();

        if (kt + 1 < kIters) loadset(kt + 1);   // flies during MFMA phase

#pragma unroll
        for (int ks = 0; ks < 2; ++ks) {
            f16x8 aF[MI], bF[4];
#pragma unroll
            for (int mi = 0; mi < MI; ++mi) {
                const int r = wm + mi * 16 + ql;
                const int sc = (ks * 4 + qr) ^ (r & 7);
                aF[mi] = *(const f16x8*)&sA[r * 64 + sc * 8];
            }
#pragma unroll
            for (int ni = 0; ni < 4; ++ni) {
                const int r = wn + ni * 16 + ql;
                const int sc = (ks * 4 + qr) ^ (r & 7);
                bF[ni] = *(const f16x8*)&sB[r * 64 + sc * 8];
            }
#pragma unroll
            for (int mi = 0; mi < MI; ++mi)
#pragma unroll
                for (int ni = 0; ni < 4; ++ni)
                    acc[mi][ni] = __builtin_amdgcn_mfma_f32_16x16x32_f16(
                        aF[mi], bF[ni], acc[mi][ni], 0, 0, 0);
        }
        __syncthreads();   // protect LDS before next commit
    }

    // Epilogue. C/D frag: col = lane&15, row = (lane>>4)*4 + r
    const long long zC = (long long)bz * batchC;
    float rsum[MI][4];
    if (EPI == 1) {
#pragma unroll
        for (int mi = 0; mi < MI; ++mi)
#pragma unroll
            for (int r = 0; r < 4; ++r) rsum[mi][r] = 0.f;
    }

#pragma unroll
    for (int mi = 0; mi < MI; ++mi) {
        float invl[4];
        if (EPI == 2) {
#pragma unroll
            for (int r = 0; r < 4; ++r)
                invl[r] = 1.f / rowsum[bz * 2048 + m0 + wm + mi * 16 + qr * 4 + r];
        }
#pragma unroll
        for (int ni = 0; ni < 4; ++ni) {
            const f32x4 v = acc[mi][ni];
            const int mbase = m0 + wm + mi * 16 + qr * 4;
            const int n     = n0 + wn + ni * 16 + ql;
#pragma unroll
            for (int r = 0; r < 4; ++r) {
                const int m = mbase + r;
                const float val = v[r];
                if (EPI == 0) {
                    const int b = m >> 11, s = m & 2047;
                    if (n < 768)
                        OQ[(long long)m * 768 + n] = (_Float16)(val * SOFTMAX_SCALE);
                    else if (n < 1536)
                        OKk[(long long)m * 768 + (n - 768)] = (_Float16)val;
                    else
                        OV[((long long)b * 768 + (n - 1536)) * 2048 + s] = (_Float16)val;
                } else if (EPI == 1) {
                    const float e = (n <= m) ? __expf(val) : 0.f;
                    CH[zC + (long long)m * ldc + n] = (_Float16)e;
                    rsum[mi][r] += e;
                } else {
                    CF[zC + (long long)m * ldc + n] = val * invl[r];
                }
            }
        }
    }

    if (EPI == 1) {
#pragma unroll
        for (int mi = 0; mi < MI; ++mi)
#pragma unroll
            for (int r = 0; r < 4; ++r) {
                float s = rsum[mi][r];
                s += __shfl_xor(s, 1);
                s += __shfl_xor(s, 2);
                s += __shfl_xor(s, 4);
                s += __shfl_xor(s, 8);
                if (ql == 0) {
                    const int m = m0 + wm + mi * 16 + qr * 4 + r;
                    atomicAdd(&rowsum[bz * 2048 + m], s);
                }
            }
    }
}

// One thread per 8 elements: converts x and the 3 weights, zeroes rowsum.
__global__ __launch_bounds__(256) void cvt_all(
    const float* __restrict__ x,  const float* __restrict__ wq,
    const float* __restrict__ wk, const float* __restrict__ wv,
    _Float16* __restrict__ xh, _Float16* __restrict__ Wh,
    float* __restrict__ rs)
{
    const int ci = blockIdx.x * 256 + threadIdx.x;
    if (ci < 8192) rs[ci] = 0.f;
    const int XC = 8192 * 768 / 8;       // 786432
    const int WC = 768 * 768 / 8;        // 73728
    const float* src; _Float16* dst; int lo;
    if (ci < XC) {
        src = x; dst = xh; lo = ci;
    } else {
        const int j = ci - XC;
        const int w = j / WC;            // wave-uniform (region >> wave)
        lo = j - w * WC;
        src = (w == 0) ? wq : (w == 1) ? wk : wv;
        dst = Wh + (long long)w * (768 * 768);
    }
    const float4 v0 = ((const float4*)src)[lo * 2];
    const float4 v1 = ((const float4*)src)[lo * 2 + 1];
    f16x8 o = { (_Float16)v0.x, (_Float16)v0.y, (_Float16)v0.z, (_Float16)v0.w,
                (_Float16)v1.x, (_Float16)v1.y, (_Float16)v1.z, (_Float16)v1.w };
    ((f16x8*)dst)[lo] = o;
}

extern "C" void kernel_launch(void* const* d_in, const int* in_sizes, int n_in,
                              void* d_out, int out_size, void* d_ws, size_t ws_size,
                              hipStream_t stream) {
    const float* x  = (const float*)d_in[0];
    const float* wq = (const float*)d_in[1];
    const float* wk = (const float*)d_in[2];
    const float* wv = (const float*)d_in[3];
    float* out = (float*)d_out;
    char* ws = (char*)d_ws;

    size_t off = 0;
    auto alloc = [&](size_t bytes) {
        void* p = ws + off;
        off = (off + bytes + 255) & ~(size_t)255;
        return p;
    };
    _Float16* xh = (_Float16*)alloc(8192ll * 768 * 2);
    _Float16* Wh = (_Float16*)alloc(2304ll * 768 * 2);
    _Float16* Qh = (_Float16*)alloc(8192ll * 768 * 2);   // pre-scaled by 1/sqrt(d)
    _Float16* Kh = (_Float16*)alloc(8192ll * 768 * 2);
    _Float16* Vt = (_Float16*)alloc(4ll * 768 * 2048 * 2);     // V^T per batch
    _Float16* E  = (_Float16*)alloc(4ll * 2048 * 2048 * 2);    // exp(scores) f16
    float*    rs = (float*)   alloc(8192ll * 4);               // row sums

    // converts + rowsum zeroing, one dispatch
    cvt_all<<<(8192 * 768 / 8 + 3 * 768 * 768 / 8) / 256, 256, 0, stream>>>(
        x, wq, wk, wv, xh, Wh, rs);

    // Y = x * W^T : M=8192, N=2304, K=768  (256x128 tiles)
    gemm_bt<0, 8><<<dim3(18, 32, 1), 256, 0, stream>>>(
        xh, Wh, nullptr, nullptr, Qh, Kh, Vt, nullptr,
        768, 768, 768, 0, 0, 0, 0);

    // E = exp(Q K^T) per batch, rowsum atomics (lower-triangle 256x128 tiles)
    gemm_bt<1, 8><<<dim3(72 * 4, 1, 1), 256, 0, stream>>>(
        Qh, Kh, nullptr, E, nullptr, nullptr, nullptr, rs,
        768, 768, 768, 2048, 2048ll * 768, 2048ll * 768, 2048ll * 2048);

    // O = (E * V^T^T) / rowsum per batch : 128x128 tiles, K causal-truncated
    gemm_bt<2, 4><<<dim3(6, 16, 4), 256, 0, stream>>>(
        E, Vt, out, nullptr, nullptr, nullptr, nullptr, rs,
        2048, 2048, 2048, 768, 2048ll * 2048, 768ll * 2048, 2048ll * 768);
}

// Round 7
// 208.333 us; speedup vs baseline: 1.8357x; 1.0419x over previous
//
#include <hip/hip_runtime.h>
#include <hip/hip_bf16.h>
#include <cstdint>
#include <cstddef>

// B=4, S=2048, D=768 causal attention, fp32 in/out, f16 MFMA compute.
// cvt(+zero rowsum) -> QKV GEMM (Q pre-scaled) -> QK^T GEMM (exp+rowsum
// atomics) -> PV GEMM (*1/rowsum). No separate softmax pass.
// GEMM: r3-best config: wave tile MI*16 x 64, block MI*32 x 128, BK=64,
// XOR-swizzled single LDS buffer, register-prefetch pipeline.
// g0/g1: MI=4 (128x128 tiles). g2: MI=2 (64x128) -> 768 blocks, halved
// heavy-block wall time, ~4 blocks/CU -> tail + latency-hiding fix.

typedef _Float16 f16x8 __attribute__((ext_vector_type(8)));
typedef float    f32x4 __attribute__((ext_vector_type(4)));

#define SOFTMAX_SCALE 0.036084391824351615f  // 1/sqrt(768)

// EPI 0: QKV projection epilogue (Q*scale/K flat f16, V transposed per batch)
// EPI 1: E = exp(S) f16 (causal-masked), rowsum atomics; triangular grid
// EPI 2: output fp32 * 1/rowsum[m], K-loop truncated causally, heavy-tm first
// MI: A-fragment rows per wave (wave tile = MI*16 x 64; block = MI*32 x 128)
template <int EPI, int MI>
__global__ __launch_bounds__(256, 2) void gemm_bt(
    const _Float16* __restrict__ A, const _Float16* __restrict__ B,
    float* __restrict__ CF, _Float16* __restrict__ CH,
    _Float16* __restrict__ OQ, _Float16* __restrict__ OKk, _Float16* __restrict__ OV,
    float* __restrict__ rowsum,
    int K, int lda, int ldb, int ldc,
    long long batchA, long long batchB, long long batchC)
{
    constexpr int BM = MI * 32;          // block rows
    int tm, tn, bz;
    if (EPI == 1) {
        // triangular decode: 136 lower-triangle 128x128 tiles per batch
        const int idx = blockIdx.x;
        bz = idx / 136;
        const int t = idx - bz * 136;
        tm = (int)((__builtin_sqrtf(8.f * t + 1.f) - 1.f) * 0.5f);
        while ((tm + 1) * (tm + 2) / 2 <= t) ++tm;
        while (tm * (tm + 1) / 2 > t) --tm;
        tn = t - tm * (tm + 1) / 2;
    } else if (EPI == 2) {
        tm = (int)gridDim.y - 1 - (int)blockIdx.y;   // heavy tiles first
        tn = blockIdx.x; bz = blockIdx.z;
    } else {
        tm = blockIdx.y; tn = blockIdx.x; bz = blockIdx.z;
    }

    const int m0 = tm * BM, n0 = tn * 128;
    const int tid  = threadIdx.x;
    const int lane = tid & 63, wave = tid >> 6;
    const int wm = (wave >> 1) * (MI * 16), wn = (wave & 1) * 64;
    const int qr = lane >> 4, ql = lane & 15;

    __shared__ _Float16 sA[BM * 64];
    __shared__ _Float16 sB[128 * 64];

    const _Float16* Ab = A + (long long)bz * batchA + (long long)m0 * lda;
    const _Float16* Bb = B + (long long)bz * batchB + (long long)n0 * ldb;

    int kIters = K / 64;
    if (EPI == 2) kIters = (m0 + BM) / 64;   // E is zero beyond row index

    f32x4 acc[MI][4];
#pragma unroll
    for (int i = 0; i < MI; ++i)
#pragma unroll
        for (int j = 0; j < 4; ++j) acc[i][j] = (f32x4){0.f, 0.f, 0.f, 0.f};

    // Staging: 16B chunk c = t*256 + tid at LDS slot c; slot c holds global
    // chunk (c&7)^(row&7) of row=c>>3 (XOR swizzle; readers XOR the same
    // way -> conflict-free b128 on both sides; measured 0 conflicts).
    int sraA[MI], sgcA[MI], sraB[4], sgcB[4];
#pragma unroll
    for (int t = 0; t < MI; ++t) {
        const int c = t * 256 + tid, r = c >> 3;
        sraA[t] = r; sgcA[t] = (c & 7) ^ (r & 7);
    }
#pragma unroll
    for (int t = 0; t < 4; ++t) {
        const int c = t * 256 + tid, r = c >> 3;
        sraB[t] = r; sgcB[t] = (c & 7) ^ (r & 7);
    }

    f16x8 pa[MI], pb[4];
    auto loadset = [&](int kt) {
        const int kk = kt * 64;
#pragma unroll
        for (int t = 0; t < MI; ++t)
            pa[t] = *(const f16x8*)(Ab + (long long)sraA[t] * lda + kk + sgcA[t] * 8);
#pragma unroll
        for (int t = 0; t < 4; ++t)
            pb[t] = *(const f16x8*)(Bb + (long long)sraB[t] * ldb + kk + sgcB[t] * 8);
    };

    loadset(0);
    for (int kt = 0; kt < kIters; ++kt) {
        // commit prefetched tile kt to LDS (vmcnt waits happen here)
#pragma unroll
        for (int t = 0; t < MI; ++t) ((f16x8*)sA)[t * 256 + tid] = pa[t];
#pragma unroll
        for (int t = 0; t < 4; ++t) ((f16x8*)sB)[t * 256 + tid] = pb[t];
        __syncthreads();

        if (kt + 1 < kIters) loadset(kt + 1);   // flies during MFMA phase

#pragma unroll
        for (int ks = 0; ks < 2; ++ks) {
            f16x8 aF[MI], bF[4];
#pragma unroll
            for (int mi = 0; mi < MI; ++mi) {
                const int r = wm + mi * 16 + ql;
                const int sc = (ks * 4 + qr) ^ (r & 7);
                aF[mi] = *(const f16x8*)&sA[r * 64 + sc * 8];
            }
#pragma unroll
            for (int ni = 0; ni < 4; ++ni) {
                const int r = wn + ni * 16 + ql;
                const int sc = (ks * 4 + qr) ^ (r & 7);
                bF[ni] = *(const f16x8*)&sB[r * 64 + sc * 8];
            }
#pragma unroll
            for (int mi = 0; mi < MI; ++mi)
#pragma unroll
                for (int ni = 0; ni < 4; ++ni)
                    acc[mi][ni] = __builtin_amdgcn_mfma_f32_16x16x32_f16(
                        aF[mi], bF[ni], acc[mi][ni], 0, 0, 0);
        }
        __syncthreads();   // protect LDS before next commit
    }

    // Epilogue. C/D frag: col = lane&15, row = (lane>>4)*4 + r
    const long long zC = (long long)bz * batchC;
    float rsum[MI][4];
    if (EPI == 1) {
#pragma unroll
        for (int mi = 0; mi < MI; ++mi)
#pragma unroll
            for (int r = 0; r < 4; ++r) rsum[mi][r] = 0.f;
    }

#pragma unroll
    for (int mi = 0; mi < MI; ++mi) {
        float invl[4];
        if (EPI == 2) {
#pragma unroll
            for (int r = 0; r < 4; ++r)
                invl[r] = 1.f / rowsum[bz * 2048 + m0 + wm + mi * 16 + qr * 4 + r];
        }
#pragma unroll
        for (int ni = 0; ni < 4; ++ni) {
            const f32x4 v = acc[mi][ni];
            const int mbase = m0 + wm + mi * 16 + qr * 4;
            const int n     = n0 + wn + ni * 16 + ql;
#pragma unroll
            for (int r = 0; r < 4; ++r) {
                const int m = mbase + r;
                const float val = v[r];
                if (EPI == 0) {
                    const int b = m >> 11, s = m & 2047;
                    if (n < 768)
                        OQ[(long long)m * 768 + n] = (_Float16)(val * SOFTMAX_SCALE);
                    else if (n < 1536)
                        OKk[(long long)m * 768 + (n - 768)] = (_Float16)val;
                    else
                        OV[((long long)b * 768 + (n - 1536)) * 2048 + s] = (_Float16)val;
                } else if (EPI == 1) {
                    const float e = (n <= m) ? __expf(val) : 0.f;
                    CH[zC + (long long)m * ldc + n] = (_Float16)e;
                    rsum[mi][r] += e;
                } else {
                    CF[zC + (long long)m * ldc + n] = val * invl[r];
                }
            }
        }
    }

    if (EPI == 1) {
#pragma unroll
        for (int mi = 0; mi < MI; ++mi)
#pragma unroll
            for (int r = 0; r < 4; ++r) {
                float s = rsum[mi][r];
                s += __shfl_xor(s, 1);
                s += __shfl_xor(s, 2);
                s += __shfl_xor(s, 4);
                s += __shfl_xor(s, 8);
                if (ql == 0) {
                    const int m = m0 + wm + mi * 16 + qr * 4 + r;
                    atomicAdd(&rowsum[bz * 2048 + m], s);
                }
            }
    }
}

// One thread per 8 elements: converts x and the 3 weights, zeroes rowsum.
__global__ __launch_bounds__(256) void cvt_all(
    const float* __restrict__ x,  const float* __restrict__ wq,
    const float* __restrict__ wk, const float* __restrict__ wv,
    _Float16* __restrict__ xh, _Float16* __restrict__ Wh,
    float* __restrict__ rs)
{
    const int ci = blockIdx.x * 256 + threadIdx.x;
    if (ci < 8192) rs[ci] = 0.f;
    const int XC = 8192 * 768 / 8;       // 786432
    const int WC = 768 * 768 / 8;        // 73728
    const float* src; _Float16* dst; int lo;
    if (ci < XC) {
        src = x; dst = xh; lo = ci;
    } else {
        const int j = ci - XC;
        const int w = j / WC;            // wave-uniform (region >> wave)
        lo = j - w * WC;
        src = (w == 0) ? wq : (w == 1) ? wk : wv;
        dst = Wh + (long long)w * (768 * 768);
    }
    const float4 v0 = ((const float4*)src)[lo * 2];
    const float4 v1 = ((const float4*)src)[lo * 2 + 1];
    f16x8 o = { (_Float16)v0.x, (_Float16)v0.y, (_Float16)v0.z, (_Float16)v0.w,
                (_Float16)v1.x, (_Float16)v1.y, (_Float16)v1.z, (_Float16)v1.w };
    ((f16x8*)dst)[lo] = o;
}

extern "C" void kernel_launch(void* const* d_in, const int* in_sizes, int n_in,
                              void* d_out, int out_size, void* d_ws, size_t ws_size,
                              hipStream_t stream) {
    const float* x  = (const float*)d_in[0];
    const float* wq = (const float*)d_in[1];
    const float* wk = (const float*)d_in[2];
    const float* wv = (const float*)d_in[3];
    float* out = (float*)d_out;
    char* ws = (char*)d_ws;

    size_t off = 0;
    auto alloc = [&](size_t bytes) {
        void* p = ws + off;
        off = (off + bytes + 255) & ~(size_t)255;
        return p;
    };
    _Float16* xh = (_Float16*)alloc(8192ll * 768 * 2);
    _Float16* Wh = (_Float16*)alloc(2304ll * 768 * 2);
    _Float16* Qh = (_Float16*)alloc(8192ll * 768 * 2);   // pre-scaled by 1/sqrt(d)
    _Float16* Kh = (_Float16*)alloc(8192ll * 768 * 2);
    _Float16* Vt = (_Float16*)alloc(4ll * 768 * 2048 * 2);     // V^T per batch
    _Float16* E  = (_Float16*)alloc(4ll * 2048 * 2048 * 2);    // exp(scores) f16
    float*    rs = (float*)   alloc(8192ll * 4);               // row sums

    // converts + rowsum zeroing, one dispatch
    cvt_all<<<(8192 * 768 / 8 + 3 * 768 * 768 / 8) / 256, 256, 0, stream>>>(
        x, wq, wk, wv, xh, Wh, rs);

    // Y = x * W^T : M=8192, N=2304, K=768  (128x128 tiles)
    gemm_bt<0, 4><<<dim3(18, 64, 1), 256, 0, stream>>>(
        xh, Wh, nullptr, nullptr, Qh, Kh, Vt, nullptr,
        768, 768, 768, 0, 0, 0, 0);

    // E = exp(Q K^T) per batch, rowsum atomics (lower-triangle 128x128 tiles)
    gemm_bt<1, 4><<<dim3(136 * 4, 1, 1), 256, 0, stream>>>(
        Qh, Kh, nullptr, E, nullptr, nullptr, nullptr, rs,
        768, 768, 768, 2048, 2048ll * 768, 2048ll * 768, 2048ll * 2048);

    // O = (E * V^T^T) / rowsum per batch : 64x128 tiles, K causal-truncated
    gemm_bt<2, 2><<<dim3(6, 32, 4), 256, 0, stream>>>(
        E, Vt, out, nullptr, nullptr, nullptr, nullptr, rs,
        2048, 2048, 2048, 768, 2048ll * 2048, 768ll * 2048, 2048ll * 768);
}